// Round 4
// baseline (104.504 us; speedup 1.0000x reference)
//
#include <hip/hip_runtime.h>

// Problem shape (fixed by setup_inputs): B=1, S=8192, H=32, D=128, Snew=128
constexpr int S = 8192, Snew = 128, H = 32, D = 128;
constexpr int TOKENS = S * H;                     // 262144 tokens per tensor
constexpr int GROUPS = TOKENS * (D / 4);          // 8388608 vec4 groups per tensor
constexpr int BLOCKS_HALF = 1024;                 // blocks per tensor
constexpr int THREADS_HALF = BLOCKS_HALF * 256;   // 262144 threads per tensor
constexpr int ITERS = GROUPS / THREADS_HALF;      // exactly 32
constexpr int GROUPS_PER_S = H * (D / 4);         // 1024 groups per seq position
constexpr float QMINf = -128.0f, QMAXf = 127.0f;
constexpr float EPSf = 1.1920928955078125e-07f;   // np.finfo(float32).eps

typedef int   i32x4 __attribute__((ext_vector_type(4)));
typedef float f32x4 __attribute__((ext_vector_type(4)));

// One fused kernel. Grid = 2048 blocks x 256 threads.
//   blocks [0,1024)    -> K tensor;  blocks [1024,2048) -> V tensor.
// Part 1: each of the block's 4 waves quantizes+dequantizes one new token
//         into the update window [start, start+Snew).
// Part 2: the block streams its 1/1024 share of the tensor's cache,
//         dequantizing int8(-as-int32) -> f32, skipping the window.
// The two parts write disjoint output regions -> no ordering needed.
// R4 A/B: nontemporal load/store hints REMOVED (plain dwordx4), matching the
// 6.29 TB/s copy-ubench access pattern exactly. Everything else unchanged.
__global__ __launch_bounds__(256) void fused_kv(
    const float* __restrict__ k_val, const float* __restrict__ v_val,
    const int* __restrict__ k_cache, const int* __restrict__ v_cache,
    const float* __restrict__ k_scales, const float* __restrict__ v_scales,
    const int* __restrict__ k_zp, const int* __restrict__ v_zp,
    const int* __restrict__ input_pos, float* __restrict__ out)
{
    const int b      = blockIdx.x;
    const int tensor = (b >= BLOCKS_HALF);
    const int bh     = tensor ? b - BLOCKS_HALF : b;

    // dynamic_update_slice clamps start into [0, S - Snew]
    long long start = input_pos[0];
    if (start < 0) start = 0;
    if (start > (long long)(S - Snew)) start = S - Snew;

    // ---- Part 1: quantize one new token per wave (4 tokens per block) ----
    {
        const int lane = threadIdx.x & 63;
        const int wv   = threadIdx.x >> 6;
        const int tok  = bh * 4 + wv;                 // s_new*H + h, 0..4095
        const float* src = tensor ? v_val : k_val;
        const float2 x = ((const float2*)(src + (size_t)tok * D))[lane];
        float mn = fminf(x.x, x.y), mx = fmaxf(x.x, x.y);
        #pragma unroll
        for (int off = 1; off < 64; off <<= 1) {
            mn = fminf(mn, __shfl_xor(mn, off, 64));
            mx = fmaxf(mx, __shfl_xor(mx, off, 64));
        }
        mn = fminf(mn, 0.0f);
        mx = fmaxf(mx, 0.0f);
        const float scale = fmaxf((mx - mn) / 255.0f, EPSf);
        const float dmin = mn / scale, dmax = mx / scale;
        float zp = ((QMINf + dmin) + (QMAXf + dmax) > 0.0f) ? (QMINf - dmin)
                                                            : (QMAXf - dmax);
        zp = rintf(fminf(fmaxf(zp, QMINf), QMAXf));   // clip then round half-even
        const float q0 = fminf(fmaxf(rintf(x.x / scale) + zp, QMINf), QMAXf);
        const float q1 = fminf(fmaxf(rintf(x.y / scale) + zp, QMINf), QMAXf);
        const int s_new = tok >> 5;                   // / H
        const int h     = tok & (H - 1);
        const size_t off_el =
            ((size_t)tensor * TOKENS + (size_t)(start + s_new) * H + h) * (size_t)D;
        ((float2*)(out + off_el))[lane] =
            make_float2((q0 - zp) * scale, (q1 - zp) * scale);
    }

    // ---- Part 2: bulk dequant of this tensor's cache (skip the window) ----
    const i32x4* __restrict__ c4  = (const i32x4*)(tensor ? v_cache : k_cache);
    const float* __restrict__ scl = tensor ? v_scales : k_scales;
    const int*   __restrict__ zps = tensor ? v_zp : k_zp;
    f32x4* __restrict__ o4 = (f32x4*)out + (size_t)tensor * GROUPS;

    const unsigned g_lo  = (unsigned)start * GROUPS_PER_S;  // window start (groups)
    const unsigned g_len = (unsigned)Snew * GROUPS_PER_S;   // 131072 groups

    const int tid = bh * 256 + (int)threadIdx.x;            // 0..262143
    #pragma unroll 8
    for (int it = 0; it < ITERS; ++it) {
        const int i     = tid + it * THREADS_HALF;
        const int token = i >> 5;                           // 32 groups per token
        const i32x4 q4    = c4[i];
        const float scale = scl[token];
        const float zp    = (float)zps[token];
        f32x4 o;
        o.x = ((float)q4.x - zp) * scale;
        o.y = ((float)q4.y - zp) * scale;
        o.z = ((float)q4.z - zp) * scale;
        o.w = ((float)q4.w - zp) * scale;
        if ((unsigned)i - g_lo >= g_len)                    // outside update window
            o4[i] = o;
    }
}

extern "C" void kernel_launch(void* const* d_in, const int* in_sizes, int n_in,
                              void* d_out, int out_size, void* d_ws, size_t ws_size,
                              hipStream_t stream) {
    (void)in_sizes; (void)n_in; (void)out_size; (void)d_ws; (void)ws_size;
    const int*   input_pos = (const int*)d_in[0];
    const float* k_val     = (const float*)d_in[1];
    const float* v_val     = (const float*)d_in[2];
    const int*   k_cache   = (const int*)d_in[3];
    const int*   v_cache   = (const int*)d_in[4];
    const float* k_scales  = (const float*)d_in[5];
    const float* v_scales  = (const float*)d_in[6];
    const int*   k_zp      = (const int*)d_in[7];
    const int*   v_zp      = (const int*)d_in[8];
    float*       out       = (float*)d_out;

    fused_kv<<<2 * BLOCKS_HALF, 256, 0, stream>>>(
        k_val, v_val, k_cache, v_cache, k_scales, v_scales,
        k_zp, v_zp, input_pos, out);
}

// Round 5
// 98.033 us; speedup vs baseline: 1.0660x; 1.0660x over previous
//
#include <hip/hip_runtime.h>

// Problem shape (fixed by setup_inputs): B=1, S=8192, H=32, D=128, Snew=128
constexpr int S = 8192, Snew = 128, H = 32, D = 128;
constexpr int TOKENS = S * H;                     // 262144 tokens per tensor
constexpr int GROUPS = TOKENS * (D / 4);          // 8388608 vec4 groups per tensor
constexpr int BLOCKS_HALF = 1024;                 // blocks per tensor
constexpr int THREADS_HALF = BLOCKS_HALF * 256;   // 262144 threads per tensor
constexpr int ITERS = GROUPS / THREADS_HALF;      // exactly 32
constexpr int GROUPS_PER_S = H * (D / 4);         // 1024 groups per seq position
constexpr float QMINf = -128.0f, QMAXf = 127.0f;
constexpr float EPSf = 1.1920928955078125e-07f;   // np.finfo(float32).eps

typedef int   i32x4 __attribute__((ext_vector_type(4)));
typedef float f32x4 __attribute__((ext_vector_type(4)));

// One fused kernel. Grid = 2048 blocks x 256 threads.
//   blocks [0,1024)    -> K tensor;  blocks [1024,2048) -> V tensor.
// Part 1: each of the block's 4 waves quantizes+dequantizes one new token
//         into the update window [start, start+Snew).
// Part 2: the block streams its 1/1024 share of the tensor's cache,
//         dequantizing int8(-as-int32) -> f32, skipping the window.
// The two parts write disjoint output regions -> no ordering needed.
//
// R5: restore R3's nontemporal hints — R4 A/B showed removing them costs
// +5.7 us (104.5 vs 98.8). nt stores skip L2 write-allocate (no dirty-line
// evictions competing with the read stream); nt loads mark evict-first.
__global__ __launch_bounds__(256) void fused_kv(
    const float* __restrict__ k_val, const float* __restrict__ v_val,
    const int* __restrict__ k_cache, const int* __restrict__ v_cache,
    const float* __restrict__ k_scales, const float* __restrict__ v_scales,
    const int* __restrict__ k_zp, const int* __restrict__ v_zp,
    const int* __restrict__ input_pos, float* __restrict__ out)
{
    const int b      = blockIdx.x;
    const int tensor = (b >= BLOCKS_HALF);
    const int bh     = tensor ? b - BLOCKS_HALF : b;

    // dynamic_update_slice clamps start into [0, S - Snew]
    long long start = input_pos[0];
    if (start < 0) start = 0;
    if (start > (long long)(S - Snew)) start = S - Snew;

    // ---- Part 1: quantize one new token per wave (4 tokens per block) ----
    {
        const int lane = threadIdx.x & 63;
        const int wv   = threadIdx.x >> 6;
        const int tok  = bh * 4 + wv;                 // s_new*H + h, 0..4095
        const float* src = tensor ? v_val : k_val;
        const float2 x = ((const float2*)(src + (size_t)tok * D))[lane];
        float mn = fminf(x.x, x.y), mx = fmaxf(x.x, x.y);
        #pragma unroll
        for (int off = 1; off < 64; off <<= 1) {
            mn = fminf(mn, __shfl_xor(mn, off, 64));
            mx = fmaxf(mx, __shfl_xor(mx, off, 64));
        }
        mn = fminf(mn, 0.0f);
        mx = fmaxf(mx, 0.0f);
        const float scale = fmaxf((mx - mn) / 255.0f, EPSf);
        const float dmin = mn / scale, dmax = mx / scale;
        float zp = ((QMINf + dmin) + (QMAXf + dmax) > 0.0f) ? (QMINf - dmin)
                                                            : (QMAXf - dmax);
        zp = rintf(fminf(fmaxf(zp, QMINf), QMAXf));   // clip then round half-even
        const float q0 = fminf(fmaxf(rintf(x.x / scale) + zp, QMINf), QMAXf);
        const float q1 = fminf(fmaxf(rintf(x.y / scale) + zp, QMINf), QMAXf);
        const int s_new = tok >> 5;                   // / H
        const int h     = tok & (H - 1);
        const size_t off_el =
            ((size_t)tensor * TOKENS + (size_t)(start + s_new) * H + h) * (size_t)D;
        ((float2*)(out + off_el))[lane] =
            make_float2((q0 - zp) * scale, (q1 - zp) * scale);
    }

    // ---- Part 2: bulk dequant of this tensor's cache (skip the window) ----
    const i32x4* __restrict__ c4  = (const i32x4*)(tensor ? v_cache : k_cache);
    const float* __restrict__ scl = tensor ? v_scales : k_scales;
    const int*   __restrict__ zps = tensor ? v_zp : k_zp;
    f32x4* __restrict__ o4 = (f32x4*)out + (size_t)tensor * GROUPS;

    const unsigned g_lo  = (unsigned)start * GROUPS_PER_S;  // window start (groups)
    const unsigned g_len = (unsigned)Snew * GROUPS_PER_S;   // 131072 groups

    const int tid = bh * 256 + (int)threadIdx.x;            // 0..262143
    #pragma unroll 8
    for (int it = 0; it < ITERS; ++it) {
        const int i     = tid + it * THREADS_HALF;
        const int token = i >> 5;                           // 32 groups per token
        const i32x4 q4    = __builtin_nontemporal_load(c4 + i);
        const float scale = scl[token];
        const float zp    = (float)zps[token];
        f32x4 o;
        o.x = ((float)q4.x - zp) * scale;
        o.y = ((float)q4.y - zp) * scale;
        o.z = ((float)q4.z - zp) * scale;
        o.w = ((float)q4.w - zp) * scale;
        if ((unsigned)i - g_lo >= g_len)                    // outside update window
            __builtin_nontemporal_store(o, o4 + i);
    }
}

extern "C" void kernel_launch(void* const* d_in, const int* in_sizes, int n_in,
                              void* d_out, int out_size, void* d_ws, size_t ws_size,
                              hipStream_t stream) {
    (void)in_sizes; (void)n_in; (void)out_size; (void)d_ws; (void)ws_size;
    const int*   input_pos = (const int*)d_in[0];
    const float* k_val     = (const float*)d_in[1];
    const float* v_val     = (const float*)d_in[2];
    const int*   k_cache   = (const int*)d_in[3];
    const int*   v_cache   = (const int*)d_in[4];
    const float* k_scales  = (const float*)d_in[5];
    const float* v_scales  = (const float*)d_in[6];
    const int*   k_zp      = (const int*)d_in[7];
    const int*   v_zp      = (const int*)d_in[8];
    float*       out       = (float*)d_out;

    fused_kv<<<2 * BLOCKS_HALF, 256, 0, stream>>>(
        k_val, v_val, k_cache, v_cache, k_scales, v_scales,
        k_zp, v_zp, input_pos, out);
}